// Round 2
// baseline (1144.003 us; speedup 1.0000x reference)
//
#include <hip/hip_runtime.h>
#include <hip/hip_bf16.h>

#define NV 100000
#define EPSB 1e-5f

typedef unsigned short u16;
typedef unsigned int u32;

__device__ __forceinline__ float bflo(u32 u) {
  union { u32 i; float f; } v; v.i = u << 16; return v.f;
}
__device__ __forceinline__ float bfhi(u32 u) {
  union { u32 i; float f; } v; v.i = u & 0xffff0000u; return v.f;
}
__device__ __forceinline__ float bf2f(u16 u) {
  union { u32 i; float f; } v; v.i = ((u32)u) << 16; return v.f;
}
__device__ __forceinline__ u16 f2bf(float f) {
  union { float f; u32 i; } v; v.f = f;
  u32 r = v.i + 0x7fffu + ((v.i >> 16) & 1u);  // RNE
  return (u16)(r >> 16);
}
__device__ __forceinline__ u32 pack2(float x, float y) {
  return ((u32)f2bf(x)) | (((u32)f2bf(y)) << 16);
}
// uniform broadcast from a lane: v_readlane -> SGPR operand (free in FMA)
__device__ __forceinline__ float bcastf(float v, int l) {
  union { float f; int i; } a; a.f = v;
  union { int i; float f; } b; b.i = __builtin_amdgcn_readlane(a.i, l);
  return b.f;
}

// ---------------------------------------------------------------------------
// K0: detect key_mask element width. int32/f32 mode: all dwords in {0,1,1.0f}.
// bool-byte data essentially never matches over 4096 dwords.
// ---------------------------------------------------------------------------
__global__ void k0_detect(const u32* __restrict__ km, int* __restrict__ flag) {
  int bad = 0;
  for (int i = threadIdx.x; i < 4096; i += 256) {
    u32 v = km[i];
    bad |= (v != 0u && v != 1u && v != 0x3F800000u) ? 1 : 0;
  }
  unsigned long long m = __ballot(bad != 0);
  __shared__ int sbad[4];
  if ((threadIdx.x & 63) == 0) sbad[threadIdx.x >> 6] = (m != 0ull);
  __syncthreads();
  if (threadIdx.x == 0) flag[0] = !(sbad[0] | sbad[1] | sbad[2] | sbad[3]);
}

// ---------------------------------------------------------------------------
// K1: gather attention.  wave = one voxel, lane = channel.
// Score path fully fp32 (Wq, Wk, KF, QK). Wv/Wo bf16-packed (post-softmax,
// error provably ~0.2% rel). LDS: 48KB weights + 4 x 9504B per-wave scratch.
// ---------------------------------------------------------------------------
__global__ __launch_bounds__(256) void k1_attn(
    const float* __restrict__ vf, const float* __restrict__ coords,
    const int* __restrict__ kidx, const void* __restrict__ kmaskv,
    const int* __restrict__ mflag,
    const float* __restrict__ wq, const float* __restrict__ bq,
    const float* __restrict__ wk,
    const float* __restrict__ wv, const float* __restrict__ bv,
    const float* __restrict__ wo, const float* __restrict__ bo,
    const float* __restrict__ qpw, const float* __restrict__ qpb,
    const float* __restrict__ kpw, const float* __restrict__ kpb,
    float* __restrict__ x1pre, float* __restrict__ stats)
{
  extern __shared__ char smem[];
  float* WQT = (float*)smem;            // [c][i] = wq[i][c], fp32 16KB
  float* WKN = WQT + 4096;              // [i][c] natural,    fp32 16KB
  u32*   WVP = (u32*)(WKN + 4096);      // [c2][i] packed bf16 pair, 8KB
  u32*   WOP = WVP + 2048;              // [c2][i] packed bf16 pair, 8KB
  const int tid = threadIdx.x, wid = tid >> 6, lane = tid & 63;

  for (int t = tid; t < 4096; t += 256) {
    int i = t >> 6, c = t & 63;
    WQT[c*64 + i] = wq[t];
    WKN[t]        = wk[t];
  }
  for (int t = tid; t < 2048; t += 256) {
    int c2 = t >> 6, i = t & 63;               // t == c2*64+i
    WVP[t] = pack2(wv[i*64 + 2*c2], wv[i*64 + 2*c2 + 1]);
    WOP[t] = pack2(wo[i*64 + 2*c2], wo[i*64 + 2*c2 + 1]);
  }
  __syncthreads();

  float* wbase = (float*)(smem + 49152) + wid * 2376;
  float* KF = wbase;          // [32][66] fp32, pitch 66 -> 2-way max (free)
  float* QK = wbase + 2112;   // [4][66]  fp32

  const float qp0 = qpw[lane*3], qp1 = qpw[lane*3+1], qp2 = qpw[lane*3+2], qpbl = qpb[lane];
  const float kp0 = kpw[lane*3], kp1 = kpw[lane*3+1], kp2 = kpw[lane*3+2], kpbl = kpb[lane];
  const float bql = bq[lane], bvl = bv[lane], bol = bo[lane];
  const int kl = lane & 31, hb = lane >> 5, hh = lane >> 4;
  const int mode4 = mflag[0];                      // wave-uniform
  const u32* km32 = (const u32*)kmaskv;
  const unsigned char* km8 = (const unsigned char*)kmaskv;
  float ssum = 0.f, ssq = 0.f;

  const int stride = gridDim.x << 2;
  for (int n = blockIdx.x*4 + wid; n < NV; n += stride) {
    const float cn0 = coords[n*3], cn1 = coords[n*3+1], cn2 = coords[n*3+2];
    const int   idx = kidx[n*32 + kl];
    u32 mk;
    if (mode4) mk = (km32[n*32 + kl] != 0u);
    else       mk = (km8[n*32 + kl]  != 0u);
    const float rc0 = coords[idx*3]   - cn0;
    const float rc1 = coords[idx*3+1] - cn1;
    const float rc2 = coords[idx*3+2] - cn2;
    const float vfl = vf[n*64 + lane];

    // issue all 32 neighbor-feature gathers up front
    float g[32];
    #pragma unroll
    for (int k2 = 0; k2 < 32; ++k2) {
      int ik = __builtin_amdgcn_readlane(idx, k2);
      g[k2] = vf[ik*64 + lane];
    }

    // query = vf + relu(coords @ qpw^T + qpb)
    float query = vfl + fmaxf(fmaf(qp0,cn0,fmaf(qp1,cn1,fmaf(qp2,cn2,qpbl))), 0.f);

    // q = Wq query + bq  (fp32, 4 independent chains)
    float qa0 = bql, qa1 = 0.f, qa2 = 0.f, qa3 = 0.f;
    #pragma unroll
    for (int c = 0; c < 16; ++c) {
      qa0 = fmaf(WQT[(c   )*64+lane], bcastf(query, c   ), qa0);
      qa1 = fmaf(WQT[(c+16)*64+lane], bcastf(query, c+16), qa1);
      qa2 = fmaf(WQT[(c+32)*64+lane], bcastf(query, c+32), qa2);
      qa3 = fmaf(WQT[(c+48)*64+lane], bcastf(query, c+48), qa3);
    }
    const float qacc = (qa0+qa1) + (qa2+qa3);

    // qk[h][c] = (Wk_h^T q_h)[c] / 4   (4 independent chains by head)
    float qkh0=0.f, qkh1=0.f, qkh2=0.f, qkh3=0.f;
    #pragma unroll
    for (int i = 0; i < 16; ++i) {
      qkh0 = fmaf(WKN[(i   )*64+lane], bcastf(qacc, i   ), qkh0);
      qkh1 = fmaf(WKN[(i+16)*64+lane], bcastf(qacc, i+16), qkh1);
      qkh2 = fmaf(WKN[(i+32)*64+lane], bcastf(qacc, i+32), qkh2);
      qkh3 = fmaf(WKN[(i+48)*64+lane], bcastf(qacc, i+48), qkh3);
    }
    QK[       lane] = qkh0*0.25f;
    QK[ 66  + lane] = qkh1*0.25f;
    QK[132  + lane] = qkh2*0.25f;
    QK[198  + lane] = qkh3*0.25f;

    // key features: gathered + relu(pos-emb) -> LDS fp32
    #pragma unroll
    for (int k2 = 0; k2 < 32; ++k2) {
      float r0 = bcastf(rc0,k2), r1 = bcastf(rc1,k2), r2 = bcastf(rc2,k2);
      float pe = fmaxf(fmaf(kp0,r0,fmaf(kp1,r1,fmaf(kp2,r2,kpbl))), 0.f);
      KF[k2*66 + lane] = g[k2] + pe;
    }

    // scores: lane -> (k = lane&31, heads hb and hb+2); 4 chains
    float s00=0.f, s01=0.f, s10=0.f, s11=0.f;
    #pragma unroll
    for (int c = 0; c < 32; ++c) {
      float kf0 = KF[kl*66 + c], kf1 = KF[kl*66 + c + 32];
      s00 = fmaf(QK[ hb   *66 + c     ], kf0, s00);
      s01 = fmaf(QK[ hb   *66 + c + 32], kf1, s01);
      s10 = fmaf(QK[(hb+2)*66 + c     ], kf0, s10);
      s11 = fmaf(QK[(hb+2)*66 + c + 32], kf1, s11);
    }
    float sc0 = s00 + s01, sc1 = s10 + s11;
    if (mk) { sc0 = -1e30f; sc1 = -1e30f; }

    // softmax over k within each 32-lane half
    float m0 = sc0, m1 = sc1;
    #pragma unroll
    for (int off = 16; off; off >>= 1) {
      m0 = fmaxf(m0, __shfl_xor(m0, off));
      m1 = fmaxf(m1, __shfl_xor(m1, off));
    }
    float p0 = __expf(sc0 - m0), p1 = __expf(sc1 - m1);
    float s0 = p0, s1 = p1;
    #pragma unroll
    for (int off = 16; off; off >>= 1) {
      s0 += __shfl_xor(s0, off);
      s1 += __shfl_xor(s1, off);
    }
    const float a0 = p0 / s0, a1 = p1 / s1;  // attn[hb][kl], attn[hb+2][kl]

    // s[h][c] = sum_k attn[h][k] * kf[k][c]  (4 independent chains)
    float sa0=0.f, sa1=0.f, sa2=0.f, sa3=0.f;
    #pragma unroll
    for (int k2 = 0; k2 < 32; ++k2) {
      float w0 = bcastf(a0, k2);
      float w1 = bcastf(a0, k2+32);
      float w2 = bcastf(a1, k2);
      float w3 = bcastf(a1, k2+32);
      float kfv = KF[k2*66 + lane];
      sa0 = fmaf(w0,kfv,sa0); sa1 = fmaf(w1,kfv,sa1);
      sa2 = fmaf(w2,kfv,sa2); sa3 = fmaf(w3,kfv,sa3);
    }
    QK[       lane] = sa0;   // reuse QK as S buffer
    QK[ 66  + lane] = sa1;
    QK[132  + lane] = sa2;
    QK[198  + lane] = sa3;

    // ctx[i] = Wv_h s[h] + bv  (lane = i, h = i>>4), bf16 weights
    float ca0 = bvl, ca1 = 0.f;
    #pragma unroll
    for (int c2 = 0; c2 < 16; ++c2) {
      u32 wp0 = WVP[ c2    *64 + lane];
      u32 wp1 = WVP[(c2+16)*64 + lane];
      ca0 = fmaf(bflo(wp0), QK[hh*66 + 2*c2     ], ca0);
      ca0 = fmaf(bfhi(wp0), QK[hh*66 + 2*c2 +  1], ca0);
      ca1 = fmaf(bflo(wp1), QK[hh*66 + 2*c2 + 32], ca1);
      ca1 = fmaf(bfhi(wp1), QK[hh*66 + 2*c2 + 33], ca1);
    }
    const float cacc = ca0 + ca1;

    // attend = Wo ctx + bo
    float oa0 = bol, oa1 = 0.f;
    #pragma unroll
    for (int c2 = 0; c2 < 16; ++c2) {
      u32 wp0 = WOP[ c2    *64 + lane];
      u32 wp1 = WOP[(c2+16)*64 + lane];
      oa0 = fmaf(bflo(wp0), bcastf(cacc, 2*c2     ), oa0);
      oa0 = fmaf(bfhi(wp0), bcastf(cacc, 2*c2 +  1), oa0);
      oa1 = fmaf(bflo(wp1), bcastf(cacc, 2*c2 + 32), oa1);
      oa1 = fmaf(bfhi(wp1), bcastf(cacc, 2*c2 + 33), oa1);
    }
    const float aacc = oa0 + oa1;

    float x1 = vfl + aacc;
    x1pre[n*64 + lane] = x1;
    ssum += x1; ssq = fmaf(x1, x1, ssq);
  }

  // block-reduce BN1 partials -> one atomic per channel per block
  __syncthreads();
  float* red = (float*)smem;
  red[wid*64+lane] = ssum;
  red[256 + wid*64 + lane] = ssq;
  __syncthreads();
  if (wid == 0) {
    float t1 = 0.f, t2 = 0.f;
    #pragma unroll
    for (int w = 0; w < 4; ++w) { t1 += red[w*64+lane]; t2 += red[256+w*64+lane]; }
    atomicAdd(&stats[lane], t1);
    atomicAdd(&stats[64+lane], t2);
  }
}

// ---------------------------------------------------------------------------
// K3: x1 = BN1(x1pre); x2pre = x1 + FFN(x1); BN2 partials. bf16 weights.
// ---------------------------------------------------------------------------
__global__ __launch_bounds__(256) void k3_ffn(
    const float* __restrict__ x1pre, float* __restrict__ stats,
    const float* __restrict__ g1, const float* __restrict__ b1,
    const float* __restrict__ l1w, const float* __restrict__ l1b,
    const float* __restrict__ l2w, const float* __restrict__ l2b,
    float* __restrict__ x2pre)
{
  extern __shared__ char smem[];
  u16* L1T = (u16*)smem;                      // [c][f]
  u32* L2P = (u32*)(smem + 32768);            // [f2][c], 2 bf16 per u32
  const int tid = threadIdx.x, wid = tid >> 6, lane = tid & 63;

  for (int t = tid; t < 16384; t += 256) {
    int f = t >> 6, c = t & 63;
    L1T[c*256 + f] = f2bf(l1w[t]);
  }
  for (int t = tid; t < 8192; t += 256) {
    int c = t >> 7, f2 = t & 127;
    float2 w2 = *(const float2*)&l2w[c*256 + f2*2];
    L2P[f2*64 + c] = pack2(w2.x, w2.y);
  }
  __syncthreads();

  const float mean = stats[lane] * (1.f/NV);
  const float var  = stats[64+lane] * (1.f/NV) - mean*mean;
  const float sc   = rsqrtf(var + EPSB) * g1[lane];
  const float sh   = b1[lane] - mean * sc;
  const float4 l1b4 = *(const float4*)&l1b[4*lane];
  const float l2bl = l2b[lane];
  float ssum = 0.f, ssq = 0.f;

  const int stride = gridDim.x << 2;
  for (int n = blockIdx.x*4 + wid; n < NV; n += stride) {
    float x1 = x1pre[n*64+lane] * sc + sh;

    float h0 = l1b4.x, h1 = l1b4.y, h2 = l1b4.z, h3 = l1b4.w;
    #pragma unroll
    for (int c = 0; c < 64; ++c) {
      float xv = bcastf(x1, c);
      uint2 wp = *(const uint2*)&L1T[c*256 + 4*lane];
      h0 = fmaf(bflo(wp.x), xv, h0);
      h1 = fmaf(bfhi(wp.x), xv, h1);
      h2 = fmaf(bflo(wp.y), xv, h2);
      h3 = fmaf(bfhi(wp.y), xv, h3);
    }
    h0 = fmaxf(h0,0.f); h1 = fmaxf(h1,0.f); h2 = fmaxf(h2,0.f); h3 = fmaxf(h3,0.f);

    float ff = l2bl;
    #pragma unroll
    for (int f2 = 0; f2 < 128; ++f2) {
      const int sl = f2 >> 1;
      float ha, hbv;
      if ((f2 & 1) == 0) { ha = bcastf(h0, sl); hbv = bcastf(h1, sl); }
      else               { ha = bcastf(h2, sl); hbv = bcastf(h3, sl); }
      u32 wp = L2P[f2*64 + lane];
      ff = fmaf(bflo(wp), ha,  ff);
      ff = fmaf(bfhi(wp), hbv, ff);
    }

    float x2 = x1 + ff;
    x2pre[n*64+lane] = x2;
    ssum += x2; ssq = fmaf(x2, x2, ssq);
  }

  __syncthreads();
  float* red = (float*)smem;
  red[wid*64+lane] = ssum;
  red[256 + wid*64 + lane] = ssq;
  __syncthreads();
  if (wid == 0) {
    float t1 = 0.f, t2 = 0.f;
    #pragma unroll
    for (int w = 0; w < 4; ++w) { t1 += red[w*64+lane]; t2 += red[256+w*64+lane]; }
    atomicAdd(&stats[128+lane], t1);
    atomicAdd(&stats[192+lane], t2);
  }
}

// ---------------------------------------------------------------------------
// K4: x2 = BN2(x2pre); outpre = x2 @ out_w^T + out_b; BN3 partials.
// ---------------------------------------------------------------------------
__global__ __launch_bounds__(256) void k4_out(
    const float* __restrict__ x2pre, float* __restrict__ stats,
    const float* __restrict__ g2, const float* __restrict__ b2,
    const float* __restrict__ outw, const float* __restrict__ outb,
    float* __restrict__ outpre)
{
  extern __shared__ char smem[];
  u16* WT = (u16*)smem;                       // [c][o]
  const int tid = threadIdx.x, wid = tid >> 6, lane = tid & 63;
  for (int t = tid; t < 4096; t += 256) {
    int o = t >> 6, c = t & 63;
    WT[c*64+o] = f2bf(outw[t]);
  }
  __syncthreads();

  const float mean = stats[128+lane] * (1.f/NV);
  const float var  = stats[192+lane] * (1.f/NV) - mean*mean;
  const float sc   = rsqrtf(var + EPSB) * g2[lane];
  const float sh   = b2[lane] - mean * sc;
  const float obl  = outb[lane];
  float ssum = 0.f, ssq = 0.f;

  const int stride = gridDim.x << 2;
  for (int n = blockIdx.x*4 + wid; n < NV; n += stride) {
    float x2 = x2pre[n*64+lane] * sc + sh;
    float a0 = obl, a1 = 0.f;
    #pragma unroll
    for (int c = 0; c < 32; ++c) {
      a0 = fmaf(bf2f(WT[(c   )*64+lane]), bcastf(x2, c   ), a0);
      a1 = fmaf(bf2f(WT[(c+32)*64+lane]), bcastf(x2, c+32), a1);
    }
    float acc = a0 + a1;
    outpre[n*64+lane] = acc;
    ssum += acc; ssq = fmaf(acc, acc, ssq);
  }

  __syncthreads();
  float* red = (float*)smem;
  red[wid*64+lane] = ssum;
  red[256 + wid*64 + lane] = ssq;
  __syncthreads();
  if (wid == 0) {
    float t1 = 0.f, t2 = 0.f;
    #pragma unroll
    for (int w = 0; w < 4; ++w) { t1 += red[w*64+lane]; t2 += red[256+w*64+lane]; }
    atomicAdd(&stats[256+lane], t1);
    atomicAdd(&stats[320+lane], t2);
  }
}

// ---------------------------------------------------------------------------
// K5: out = relu(BN3(outpre)) -- elementwise, float4.
// ---------------------------------------------------------------------------
__global__ __launch_bounds__(256) void k5_fin(
    const float* __restrict__ outpre, const float* __restrict__ stats,
    const float* __restrict__ g3, const float* __restrict__ b3,
    float* __restrict__ out)
{
  const int t = blockIdx.x*256 + threadIdx.x;     // 131072 threads
  const int c0 = (t*4) & 63;
  float sc[4], sh[4];
  #pragma unroll
  for (int j = 0; j < 4; ++j) {
    int c = c0 + j;
    float mean = stats[256+c] * (1.f/NV);
    float var  = stats[320+c] * (1.f/NV) - mean*mean;
    sc[j] = rsqrtf(var + EPSB) * g3[c];
    sh[j] = b3[c] - mean*sc[j];
  }
  for (int i = t; i < NV*16; i += 131072) {
    float4 v = *(const float4*)&outpre[i*4];
    v.x = fmaxf(fmaf(v.x, sc[0], sh[0]), 0.f);
    v.y = fmaxf(fmaf(v.y, sc[1], sh[1]), 0.f);
    v.z = fmaxf(fmaf(v.z, sc[2], sh[2]), 0.f);
    v.w = fmaxf(fmaf(v.w, sc[3], sh[3]), 0.f);
    *(float4*)&out[i*4] = v;
  }
}

extern "C" void kernel_launch(void* const* d_in, const int* in_sizes, int n_in,
                              void* d_out, int out_size, void* d_ws, size_t ws_size,
                              hipStream_t stream) {
  (void)in_sizes; (void)n_in; (void)out_size; (void)ws_size;
  const float* vf     = (const float*)d_in[0];
  const float* coords = (const float*)d_in[1];
  const int*   kidx   = (const int*)d_in[2];
  const void*  kmask  = d_in[3];
  const float* wq  = (const float*)d_in[4];  const float* bq  = (const float*)d_in[5];
  const float* wk  = (const float*)d_in[6];  /* bk cancels in softmax */
  const float* wv  = (const float*)d_in[8];  const float* bv  = (const float*)d_in[9];
  const float* wo  = (const float*)d_in[10]; const float* bo  = (const float*)d_in[11];
  const float* qpw = (const float*)d_in[12]; const float* qpb = (const float*)d_in[13];
  const float* kpw = (const float*)d_in[14]; const float* kpb = (const float*)d_in[15];
  const float* g1  = (const float*)d_in[16]; const float* b1  = (const float*)d_in[17];
  const float* g2  = (const float*)d_in[18]; const float* b2  = (const float*)d_in[19];
  const float* l1w = (const float*)d_in[20]; const float* l1b = (const float*)d_in[21];
  const float* l2w = (const float*)d_in[22]; const float* l2b = (const float*)d_in[23];
  const float* outw= (const float*)d_in[24]; const float* outb= (const float*)d_in[25];
  const float* g3  = (const float*)d_in[26]; const float* b3  = (const float*)d_in[27];

  float* wsf    = (float*)d_ws;
  float* x1pre  = wsf;                       // [N*64]
  float* x2pre  = wsf + (size_t)NV*64;       // [N*64]
  float* outpre = x1pre;                     // alias: x1pre dead after K3
  float* stats  = wsf + (size_t)2*NV*64;     // [384]
  int*   mflag  = (int*)(stats + 384);

  hipMemsetAsync(stats, 0, 384*sizeof(float), stream);

  (void)hipFuncSetAttribute((const void*)k1_attn, hipFuncAttributeMaxDynamicSharedMemorySize, 87168);
  (void)hipFuncSetAttribute((const void*)k3_ffn,  hipFuncAttributeMaxDynamicSharedMemorySize, 65536);

  k0_detect<<<1, 256, 0, stream>>>((const u32*)kmask, mflag);
  k1_attn<<<768, 256, 87168, stream>>>(vf, coords, kidx, kmask, mflag,
      wq, bq, wk, wv, bv, wo, bo, qpw, qpb, kpw, kpb, x1pre, stats);
  k3_ffn<<<512, 256, 65536, stream>>>(x1pre, stats, g1, b1, l1w, l1b, l2w, l2b, x2pre);
  k4_out<<<1024, 256, 8192, stream>>>(x2pre, stats, g2, b2, outw, outb, outpre);
  k5_fin<<<512, 256, 0, stream>>>(outpre, stats, g3, b3, (float*)d_out);
}